// Round 1
// baseline (541.122 us; speedup 1.0000x reference)
//
#include <hip/hip_runtime.h>
#include <math.h>

#define N_PTS  262144
#define C_CH   256
#define B_SC   8
#define R_ROWS 32
#define LN_EPS 1e-5f

__device__ __forceinline__ float4 ld4(const float* p) {
    return *reinterpret_cast<const float4*>(p);
}

// lengths may arrive as int32 or int64 depending on harness x64 handling.
// Detect: if the int32-read of the first B entries sums to N, it's int32.
__device__ __forceinline__ void load_offsets(const void* lengths_raw, int* s_off) {
    const int* l32 = (const int*)lengths_raw;
    int s = 0;
    for (int i = 0; i < B_SC; ++i) s += l32[i];
    int a = 0;
    s_off[0] = 0;
    if (s == N_PTS) {
        for (int i = 0; i < B_SC; ++i) { a += l32[i]; s_off[i + 1] = a; }
    } else {
        const long long* l64 = (const long long*)lengths_raw;
        for (int i = 0; i < B_SC; ++i) { a += (int)l64[i]; s_off[i + 1] = a; }
    }
}

// ---------------- pass 0: per-scene coordinate sums ----------------
#define PARTS 32
__global__ void scene_sum_kernel(const float* __restrict__ coord,
                                 const void* __restrict__ lengths,
                                 float* __restrict__ sums) {
    __shared__ int s_off[B_SC + 1];
    __shared__ float red[4 * 3];
    if (threadIdx.x == 0) load_offsets(lengths, s_off);
    __syncthreads();
    int s = blockIdx.x / PARTS;
    int p = blockIdx.x % PARTS;
    long long st = s_off[s];
    long long len = s_off[s + 1] - st;
    int beg = (int)(st + (len * p) / PARTS);
    int end = (int)(st + (len * (p + 1)) / PARTS);
    float sx = 0.f, sy = 0.f, sz = 0.f;
    for (int r = beg + (int)threadIdx.x; r < end; r += (int)blockDim.x) {
        sx += coord[r * 3 + 0];
        sy += coord[r * 3 + 1];
        sz += coord[r * 3 + 2];
    }
    #pragma unroll
    for (int m = 1; m < 64; m <<= 1) {
        sx += __shfl_xor(sx, m, 64);
        sy += __shfl_xor(sy, m, 64);
        sz += __shfl_xor(sz, m, 64);
    }
    int wave = threadIdx.x >> 6, lane = threadIdx.x & 63;
    if (lane == 0) { red[wave * 3 + 0] = sx; red[wave * 3 + 1] = sy; red[wave * 3 + 2] = sz; }
    __syncthreads();
    if (threadIdx.x == 0) {
        atomicAdd(&sums[s * 3 + 0], red[0] + red[3] + red[6] + red[9]);
        atomicAdd(&sums[s * 3 + 1], red[1] + red[4] + red[7] + red[10]);
        atomicAdd(&sums[s * 3 + 2], red[2] + red[5] + red[8] + red[11]);
    }
}

// ---------------- main fused kernel ----------------
// One block: 256 threads = 4 waves; R_ROWS rows + 1-row halo each side.
// Wave handles a full row (64 lanes x 4 channels, float4); LN reductions are
// intra-wave shuffles (no block barrier per row).
__global__ __launch_bounds__(256, 4) void fused_xcpe_kernel(
    const float* __restrict__ feat, const float* __restrict__ coord,
    const void* __restrict__ lengths,
    const float* __restrict__ w_xyz, const float* __restrict__ b_xyz,
    const float* __restrict__ g1, const float* __restrict__ be1,
    const float* __restrict__ w_conv, const float* __restrict__ b_conv,
    const float* __restrict__ g2, const float* __restrict__ be2,
    const float* __restrict__ ssum, float* __restrict__ out)
{
    __shared__ float fbuf[(R_ROWS + 2) * C_CH];   // 34 KB
    __shared__ int s_off[B_SC + 1];
    __shared__ float s_mean[B_SC * 3];

    if (threadIdx.x == 0) load_offsets(lengths, s_off);
    __syncthreads();
    if (threadIdx.x < B_SC * 3) {
        int s = threadIdx.x / 3;
        int len = s_off[s + 1] - s_off[s];
        if (len < 1) len = 1;
        s_mean[threadIdx.x] = ssum[threadIdx.x] / (float)len;
    }
    __syncthreads();

    const int wave = threadIdx.x >> 6;
    const int lane = threadIdx.x & 63;
    const int c0 = lane << 2;
    const int row0 = blockIdx.x * R_ROWS;

    // per-channel params in registers (each lane owns 4 channels)
    float4 wxa = ld4(w_xyz + 0 * C_CH + c0);
    float4 wxb = ld4(w_xyz + 1 * C_CH + c0);
    float4 wxc = ld4(w_xyz + 2 * C_CH + c0);
    float4 bx  = ld4(b_xyz + c0);
    float4 g1v = ld4(g1 + c0);
    float4 b1v = ld4(be1 + c0);
    float4 g2v = ld4(g2 + c0);
    float4 b2v = ld4(be2 + c0);
    float4 bcv = ld4(b_conv + c0);
    float wc0[4], wc1[4], wc2[4];
    #pragma unroll
    for (int j = 0; j < 4; ++j) {
        wc0[j] = w_conv[(c0 + j) * 3 + 0];
        wc1[j] = w_conv[(c0 + j) * 3 + 1];
        wc2[j] = w_conv[(c0 + j) * 3 + 2];
    }

    // ---- phase 1: f = feat + gelu(LN1(xyz_c @ W + b)) into LDS (with halo)
    for (int idx = wave; idx < R_ROWS + 2; idx += 4) {
        int g = row0 - 1 + idx;
        if (g < 0 || g >= N_PTS) continue;   // wave-uniform
        int seg = 0;
        #pragma unroll
        for (int s = 1; s < B_SC; ++s) seg = (g >= s_off[s]) ? s : seg;
        float xc0 = coord[g * 3 + 0] - s_mean[seg * 3 + 0];
        float xc1 = coord[g * 3 + 1] - s_mean[seg * 3 + 1];
        float xc2 = coord[g * 3 + 2] - s_mean[seg * 3 + 2];
        float4 v;
        v.x = xc0 * wxa.x + xc1 * wxb.x + xc2 * wxc.x + bx.x;
        v.y = xc0 * wxa.y + xc1 * wxb.y + xc2 * wxc.y + bx.y;
        v.z = xc0 * wxa.z + xc1 * wxb.z + xc2 * wxc.z + bx.z;
        v.w = xc0 * wxa.w + xc1 * wxb.w + xc2 * wxc.w + bx.w;
        float s1 = v.x + v.y + v.z + v.w;
        float s2 = v.x * v.x + v.y * v.y + v.z * v.z + v.w * v.w;
        #pragma unroll
        for (int m = 1; m < 64; m <<= 1) {
            s1 += __shfl_xor(s1, m, 64);
            s2 += __shfl_xor(s2, m, 64);
        }
        float mu  = s1 * (1.0f / C_CH);
        float var = s2 * (1.0f / C_CH) - mu * mu;
        float rs  = rsqrtf(var + LN_EPS);
        float4 ft = ld4(feat + (size_t)g * C_CH + c0);
        float4 f;
        {
            float h;
            h = (v.x - mu) * rs * g1v.x + b1v.x;
            f.x = ft.x + 0.5f * h * (1.0f + erff(h * 0.70710678118654752f));
            h = (v.y - mu) * rs * g1v.y + b1v.y;
            f.y = ft.y + 0.5f * h * (1.0f + erff(h * 0.70710678118654752f));
            h = (v.z - mu) * rs * g1v.z + b1v.z;
            f.z = ft.z + 0.5f * h * (1.0f + erff(h * 0.70710678118654752f));
            h = (v.w - mu) * rs * g1v.w + b1v.w;
            f.w = ft.w + 0.5f * h * (1.0f + erff(h * 0.70710678118654752f));
        }
        *reinterpret_cast<float4*>(&fbuf[idx * C_CH + c0]) = f;
    }
    __syncthreads();

    // ---- phase 2: depthwise conv (k=3, scene-masked) + residual + LN2 -> out
    for (int idx = wave; idx < R_ROWS; idx += 4) {
        int i = row0 + idx;
        int seg = 0;
        #pragma unroll
        for (int s = 1; s < B_SC; ++s) seg = (i >= s_off[s]) ? s : seg;
        bool sp = (i > s_off[seg]);           // wave-uniform
        bool sn = (i + 1 < s_off[seg + 1]);   // wave-uniform
        int li = idx + 1;
        float4 f0 = *reinterpret_cast<const float4*>(&fbuf[li * C_CH + c0]);
        float4 acc;
        acc.x = f0.x * wc1[0] + bcv.x;
        acc.y = f0.y * wc1[1] + bcv.y;
        acc.z = f0.z * wc1[2] + bcv.z;
        acc.w = f0.w * wc1[3] + bcv.w;
        if (sp) {
            float4 fp4 = *reinterpret_cast<const float4*>(&fbuf[(li - 1) * C_CH + c0]);
            acc.x += fp4.x * wc0[0];
            acc.y += fp4.y * wc0[1];
            acc.z += fp4.z * wc0[2];
            acc.w += fp4.w * wc0[3];
        }
        if (sn) {
            float4 fn4 = *reinterpret_cast<const float4*>(&fbuf[(li + 1) * C_CH + c0]);
            acc.x += fn4.x * wc2[0];
            acc.y += fn4.y * wc2[1];
            acc.z += fn4.z * wc2[2];
            acc.w += fn4.w * wc2[3];
        }
        float4 ft = ld4(feat + (size_t)i * C_CH + c0);   // L2-hot re-read
        float4 y;
        y.x = ft.x + acc.x;
        y.y = ft.y + acc.y;
        y.z = ft.z + acc.z;
        y.w = ft.w + acc.w;
        float s1 = y.x + y.y + y.z + y.w;
        float s2 = y.x * y.x + y.y * y.y + y.z * y.z + y.w * y.w;
        #pragma unroll
        for (int m = 1; m < 64; m <<= 1) {
            s1 += __shfl_xor(s1, m, 64);
            s2 += __shfl_xor(s2, m, 64);
        }
        float mu  = s1 * (1.0f / C_CH);
        float var = s2 * (1.0f / C_CH) - mu * mu;
        float rs  = rsqrtf(var + LN_EPS);
        float4 o;
        o.x = (y.x - mu) * rs * g2v.x + b2v.x;
        o.y = (y.y - mu) * rs * g2v.y + b2v.y;
        o.z = (y.z - mu) * rs * g2v.z + b2v.z;
        o.w = (y.w - mu) * rs * g2v.w + b2v.w;
        *reinterpret_cast<float4*>(out + (size_t)i * C_CH + c0) = o;
    }
}

extern "C" void kernel_launch(void* const* d_in, const int* in_sizes, int n_in,
                              void* d_out, int out_size, void* d_ws, size_t ws_size,
                              hipStream_t stream) {
    const float* feat   = (const float*)d_in[0];
    const float* coord  = (const float*)d_in[1];
    const void*  lens   = (const void*)d_in[2];
    const float* w_xyz  = (const float*)d_in[3];
    const float* b_xyz  = (const float*)d_in[4];
    const float* g1     = (const float*)d_in[5];
    const float* be1    = (const float*)d_in[6];
    const float* w_conv = (const float*)d_in[7];
    const float* b_conv = (const float*)d_in[8];
    const float* g2     = (const float*)d_in[9];
    const float* be2    = (const float*)d_in[10];
    float* out  = (float*)d_out;
    float* sums = (float*)d_ws;

    hipMemsetAsync(sums, 0, B_SC * 3 * sizeof(float), stream);
    scene_sum_kernel<<<B_SC * PARTS, 256, 0, stream>>>(coord, lens, sums);
    fused_xcpe_kernel<<<N_PTS / R_ROWS, 256, 0, stream>>>(
        feat, coord, lens, w_xyz, b_xyz, g1, be1, w_conv, b_conv, g2, be2,
        sums, out);
}